// Round 5
// baseline (220.334 us; speedup 1.0000x reference)
//
#include <hip/hip_runtime.h>

#define D 64
#define EPS 2.5e-4f      // >= ~3x the fp16-split worst-case score-error bound
#define CHUNK 64         // centroids per register tile
#define INVSC 4.8828125e-4f   // 2^-11, exact

typedef __attribute__((ext_vector_type(8))) _Float16 f16x8;
typedef __attribute__((ext_vector_type(4))) float f32x4;

// prep: pre-swizzled fp16 hi/lo centroid images + c2 + zero counter.
// hi = fp16(c); lo = fp16((c - hi) * 2^11)  (scaling keeps lo normal-range).
// Layout per (chunk,kc,r): 64 lanes x 16 B contiguous -> direct coalesced
// global_load_dwordx4 per B-fragment (no LDS middleman needed).
__global__ void prep_kernel(const float* __restrict__ c, _Float16* __restrict__ chs,
                            _Float16* __restrict__ cls, float* __restrict__ c2,
                            int K, int* __restrict__ counter) {
    int t = blockIdx.x * blockDim.x + threadIdx.x;
    if (t == 0) *counter = 0;
    const int nfr = K * 8;
    if (t < nfr) {
        const int k = t >> 3, f = t & 7;
        const int ks = f >> 2, quad = f & 3;
        const int chunk = k >> 6, kc = (k >> 4) & 3, col = k & 15;
        const size_t off = (size_t)chunk * 4096 +
                           (size_t)(((kc * 2 + ks) * 64 + quad * 16 + col) * 8);
        const float* src = c + (size_t)k * D + f * 8;
        f16x8 h, l;
#pragma unroll
        for (int j = 0; j < 8; ++j) {
            float x = src[j];
            _Float16 hs = (_Float16)x;
            h[j] = hs;
            l[j] = (_Float16)((x - (float)hs) * 2048.f);
        }
        *(f16x8*)(chs + off) = h;
        *(f16x8*)(cls + off) = l;
    }
    if (t < K) {
        const float4* cp = (const float4*)(c + (size_t)t * D);
        float s = 0.f;
#pragma unroll
        for (int i = 0; i < D / 4; ++i) {
            float4 v = cp[i];
            s += v.x * v.x; s += v.y * v.y; s += v.z * v.z; s += v.w * v.w;
        }
        c2[t] = s;
    }
}

// Pass 1: fp16-hi/lo MFMA scan over ALL K + top-2 + bin write + near-tie
// flagging + exact fp32 residual for the block's 128 points.
// THIS REVISION: NO LDS STAGING. Every wave consumes the whole 512 KB
// B-table (L1/L2-resident; all 4 waves read identical addresses), so LDS
// added zero reuse — r4's CU-level ledger showed the LDS pipe (~48 us)
// was the bottleneck, not MFMA (~25 us). B-fragments now load straight
// from the swizzled global images into registers, double-buffered
// (A/B reg sets, 2-chunk unroll = static indexing), with ZERO barriers
// in the main loop. c2 loads for chunk c are issued BEFORE the prefetch
// of chunk c+1 so the compiler's auto-vmcnt never drains the prefetch.
__global__ __launch_bounds__(256, 2) void pass1_kernel(
    const float* __restrict__ action, const _Float16* __restrict__ chs,
    const _Float16* __restrict__ cls, const float* __restrict__ c2,
    const float* __restrict__ centroids, float* __restrict__ out_bin,
    float* __restrict__ out_res, int* __restrict__ counter,
    int* __restrict__ flags, int N, int K) {
    __shared__ int sbk[128];

    const int tid  = threadIdx.x;
    const int wv   = tid >> 6;
    const int lane = tid & 63;
    const int col  = lane & 15;
    const int quad = lane >> 4;
    const int mb   = blockIdx.x * 128;
    const int m0   = mb + wv * 32;
    const int NC   = K / CHUNK;            // 32

    // B-fragment pointers in 16 B units: index = chunk*512 + (kc*2+r)*64 + lane
    const f16x8* gh = (const f16x8*)chs;
    const f16x8* gl = (const f16x8*)cls;

#define LOADSET(BH, BL, cid_)                                                 \
    {                                                                         \
        const int cb = (cid_) * 512 + lane;                                   \
        _Pragma("unroll") for (int j = 0; j < 4; ++j) {                       \
            _Pragma("unroll") for (int r = 0; r < 2; ++r) {                   \
                BH[j][r] = gh[cb + (j * 2 + r) * 64];                         \
                BL[j][r] = gl[cb + (j * 2 + r) * 64];                         \
            }                                                                 \
        }                                                                     \
    }

#define LOADCC(CV, cid_)                                                      \
    {                                                                         \
        const int kb = (cid_) * CHUNK + col;                                  \
        _Pragma("unroll") for (int j = 0; j < 4; ++j) CV[j] = c2[kb + j * 16];\
    }

    f16x8 bhA[4][2], blA[4][2], bhB[4][2], blB[4][2];
    float ccvA[4], ccvB[4];

    LOADSET(bhA, blA, 0)     // chunk 0 B-frags in flight under A-conversion
    LOADCC(ccvA, 0)

    // A fragments: a' = -2a -> fp16 hi + scaled fp16 lo, in registers once.
    f16x8 ah[2][2], al[2][2];
#pragma unroll
    for (int mi = 0; mi < 2; ++mi) {
        const float* arow = action + (size_t)(m0 + mi * 16 + col) * D;
#pragma unroll
        for (int ks = 0; ks < 2; ++ks) {
            const float* src = arow + ks * 32 + quad * 8;
            f16x8 h, l;
#pragma unroll
            for (int j = 0; j < 8; ++j) {
                float x = -2.f * src[j];
                _Float16 hs = (_Float16)x;
                h[j] = hs;
                l[j] = (_Float16)((x - (float)hs) * 2048.f);
            }
            ah[mi][ks] = h;
            al[mi][ks] = l;
        }
    }

    float b1[8], b2[8];
    int   bk[8];
#pragma unroll
    for (int e = 0; e < 8; ++e) {
        b1[e] = __builtin_inff(); b2[e] = __builtin_inff(); bk[e] = 0;
    }

    const f32x4 z4 = {0.f, 0.f, 0.f, 0.f};   // persistent zero C-operand

#define COMPUTE(BH, BL, CV, c_)                                               \
    {                                                                         \
        const int kbase = (c_) * CHUNK;                                       \
        _Pragma("unroll") for (int j = 0; j < 4; ++j) {                       \
            const int kk = kbase + j * 16 + col;                              \
            const f32x4 cc4 = {CV[j], CV[j], CV[j], CV[j]};                   \
            _Pragma("unroll") for (int mi = 0; mi < 2; ++mi) {                \
                __builtin_amdgcn_s_setprio(1);                                \
                f32x4 acc2 = __builtin_amdgcn_mfma_f32_16x16x32_f16(al[mi][0], BH[j][0], z4, 0, 0, 0);  \
                acc2 = __builtin_amdgcn_mfma_f32_16x16x32_f16(ah[mi][0], BL[j][0], acc2, 0, 0, 0);      \
                f32x4 acc1 = __builtin_amdgcn_mfma_f32_16x16x32_f16(ah[mi][0], BH[j][0], cc4, 0, 0, 0); \
                acc2 = __builtin_amdgcn_mfma_f32_16x16x32_f16(al[mi][1], BH[j][1], acc2, 0, 0, 0);      \
                acc2 = __builtin_amdgcn_mfma_f32_16x16x32_f16(ah[mi][1], BL[j][1], acc2, 0, 0, 0);      \
                acc1 = __builtin_amdgcn_mfma_f32_16x16x32_f16(ah[mi][1], BH[j][1], acc1, 0, 0, 0);      \
                __builtin_amdgcn_s_setprio(0);                                \
                _Pragma("unroll") for (int r = 0; r < 4; ++r) {               \
                    const int e = mi * 4 + r;                                 \
                    const float s = fmaf(INVSC, acc2[r], acc1[r]);            \
                    b2[e] = __builtin_amdgcn_fmed3f(s, b1[e], b2[e]);         \
                    const bool better = s < b1[e];                            \
                    b1[e] = fminf(b1[e], s);                                  \
                    bk[e] = better ? kk : bk[e];                              \
                }                                                             \
            }                                                                 \
        }                                                                     \
    }

    for (int c = 0; c < NC; c += 2) {
        LOADSET(bhB, blB, c + 1)
        LOADCC(ccvB, c + 1)
        COMPUTE(bhA, blA, ccvA, c)
        {
            const int nc = (c + 2 < NC) ? (c + 2) : (NC - 1);  // tail: dead load
            LOADSET(bhA, blA, nc)
            LOADCC(ccvA, nc)
        }
        COMPUTE(bhB, blB, ccvB, c + 1)
    }
#undef COMPUTE
#undef LOADSET
#undef LOADCC

    // cross-lane top-2 merge over the 16 centroid columns
#pragma unroll
    for (int off = 1; off < 16; off <<= 1) {
#pragma unroll
        for (int e = 0; e < 8; ++e) {
            float o1 = __shfl_xor(b1[e], off, 64);
            float o2 = __shfl_xor(b2[e], off, 64);
            int   ok = __shfl_xor(bk[e], off, 64);
            bool take = (o1 < b1[e]) || (o1 == b1[e] && ok < bk[e]);
            float nb2 = take ? fminf(b1[e], o2) : fminf(b2[e], o1);
            b1[e] = take ? o1 : b1[e];
            bk[e] = take ? ok : bk[e];
            b2[e] = nb2;
        }
    }

    if (col == 0) {
#pragma unroll
        for (int e = 0; e < 8; ++e) {
            const int mi = e >> 2, r = e & 3;
            const int pl = wv * 32 + mi * 16 + quad * 4 + r;   // 0..127
            sbk[pl] = bk[e];
            out_bin[mb + pl] = (float)bk[e];
            if (b2[e] - b1[e] < EPS) {
                int idx = atomicAdd(counter, 1);
                flags[idx] = mb + pl;
            }
        }
    }
    __syncthreads();

    // exact fp32 residuals for the block's 128 points (2048 float4s).
    // 16 lanes per row -> 256 B contiguous centroid gather, coalesced I/O.
#pragma unroll
    for (int j = 0; j < 8; ++j) {
        const int idx = j * 256 + tid;
        const int row = idx >> 4, c4 = idx & 15;
        const int bki = sbk[row];
        float4 av = ((const float4*)(action + (size_t)(mb + row) * D))[c4];
        float4 cv = ((const float4*)centroids)[bki * 16 + c4];
        ((float4*)(out_res + (size_t)(mb + row) * D))[c4] =
            make_float4(av.x - cv.x, av.y - cv.y, av.z - cv.z, av.w - cv.w);
    }
}

// Exact fp32 rescan for flagged points. Block-per-point grid-stride,
// 4 interleaved dot accumulators for ILP. numpy first-min tie-break.
// (round-0 known-good version; count is ~10 so this is ~3 us)
__global__ __launch_bounds__(256) void exact_kernel(
    const float* __restrict__ action, const float* __restrict__ centroids,
    const float* __restrict__ c2, const int* __restrict__ counter,
    const int* __restrict__ flags, float* __restrict__ out_bin,
    float* __restrict__ out_res, int K) {
    __shared__ float4 sa[D / 4];
    __shared__ float  swv[4];
    __shared__ int    swk[4];
    __shared__ int    s_bk;
    const int count = *counter;
    const int tid = threadIdx.x, lane = tid & 63, wid = tid >> 6;
    for (int i = blockIdx.x; i < count; i += gridDim.x) {
        const int n = flags[i];
        __syncthreads();
        if (tid < D / 4) sa[tid] = ((const float4*)(action + (size_t)n * D))[tid];
        __syncthreads();
        float best = __builtin_inff();
        int bbk = 0x7fffffff;
        for (int k = tid; k < K; k += 256) {
            const float4* cr = (const float4*)(centroids + (size_t)k * D);
            float d0 = 0.f, d1 = 0.f, d2 = 0.f, d3 = 0.f;
#pragma unroll
            for (int q = 0; q < 4; ++q) {
                float4 a0 = sa[q * 4 + 0], c0 = cr[q * 4 + 0];
                float4 a1 = sa[q * 4 + 1], c1 = cr[q * 4 + 1];
                float4 a2 = sa[q * 4 + 2], c2v = cr[q * 4 + 2];
                float4 a3 = sa[q * 4 + 3], c3 = cr[q * 4 + 3];
                d0 = fmaf(a0.x, c0.x, d0); d0 = fmaf(a0.y, c0.y, d0);
                d0 = fmaf(a0.z, c0.z, d0); d0 = fmaf(a0.w, c0.w, d0);
                d1 = fmaf(a1.x, c1.x, d1); d1 = fmaf(a1.y, c1.y, d1);
                d1 = fmaf(a1.z, c1.z, d1); d1 = fmaf(a1.w, c1.w, d1);
                d2 = fmaf(a2.x, c2v.x, d2); d2 = fmaf(a2.y, c2v.y, d2);
                d2 = fmaf(a2.z, c2v.z, d2); d2 = fmaf(a2.w, c2v.w, d2);
                d3 = fmaf(a3.x, c3.x, d3); d3 = fmaf(a3.y, c3.y, d3);
                d3 = fmaf(a3.z, c3.z, d3); d3 = fmaf(a3.w, c3.w, d3);
            }
            float dot = (d0 + d1) + (d2 + d3);
            float s = fmaf(-2.f, dot, c2[k]);
            if (s < best) { best = s; bbk = k; }  // ascending k: first-min
        }
#pragma unroll
        for (int off = 32; off > 0; off >>= 1) {
            float ov = __shfl_down(best, off, 64);
            int   ok = __shfl_down(bbk, off, 64);
            if (ov < best || (ov == best && ok < bbk)) { best = ov; bbk = ok; }
        }
        if (lane == 0) { swv[wid] = best; swk[wid] = bbk; }
        __syncthreads();
        if (tid == 0) {
            float bb = swv[0]; int bki = swk[0];
#pragma unroll
            for (int t = 1; t < 4; ++t)
                if (swv[t] < bb || (swv[t] == bb && swk[t] < bki)) {
                    bb = swv[t]; bki = swk[t];
                }
            out_bin[n] = (float)bki;
            s_bk = bki;
        }
        __syncthreads();
        if (tid < D / 4) {
            float4 a = sa[tid];
            float4 c = ((const float4*)(centroids + (size_t)s_bk * D))[tid];
            ((float4*)(out_res + (size_t)n * D))[tid] =
                make_float4(a.x - c.x, a.y - c.y, a.z - c.z, a.w - c.w);
        }
    }
}

extern "C" void kernel_launch(void* const* d_in, const int* in_sizes, int n_in,
                              void* d_out, int out_size, void* d_ws, size_t ws_size,
                              hipStream_t stream) {
    const float* action    = (const float*)d_in[0];  // [N, 64]
    const float* centroids = (const float*)d_in[1];  // [K, 64]
    const int N = in_sizes[0] / D;  // 65536
    const int K = in_sizes[1] / D;  // 2048

    float* out_bin = (float*)d_out;      // N floats: argmin index
    float* out_res = (float*)d_out + N;  // N*D residuals

    // ws layout (~0.8 MB)
    char* w = (char*)d_ws;
    float*     c2      = (float*)w;                       // 8 KB
    int*       counter = (int*)(w + 8192);                // 4 B (padded to 256)
    int*       flags   = (int*)(w + 8448);                // N*4 = 256 KB
    _Float16*  chs     = (_Float16*)(w + 8448 + 262144);  // K*D*2 = 256 KB (swizzled)
    _Float16*  cls     = chs + (size_t)K * D;             // 256 KB (swizzled)

    prep_kernel<<<(K * 8 + 255) / 256, 256, 0, stream>>>(centroids, chs, cls,
                                                         c2, K, counter);
    pass1_kernel<<<N / 128, 256, 0, stream>>>(action, chs, cls, c2, centroids,
                                              out_bin, out_res, counter, flags,
                                              N, K);
    exact_kernel<<<256, 256, 0, stream>>>(action, centroids, c2, counter, flags,
                                          out_bin, out_res, K);
}

// Round 6
// 150.379 us; speedup vs baseline: 1.4652x; 1.4652x over previous
//
#include <hip/hip_runtime.h>

#define D 64
#define EPS 2.5e-4f      // >= ~3x the fp16-split worst-case score-error bound
#define INVSC 4.8828125e-4f   // 2^-11, exact

typedef __attribute__((ext_vector_type(8))) _Float16 f16x8;
typedef __attribute__((ext_vector_type(4))) float f32x4;

// prep: pre-swizzled fp16 hi/lo centroid images + c2 + zero counter.
// hi = fp16(c); lo = fp16((c - hi) * 2^11)  (scaling keeps lo normal-range).
// Layout per (chunk,kc,r): 64 lanes x 16 B contiguous -> direct coalesced
// global_load_dwordx4 per B-fragment.
__global__ void prep_kernel(const float* __restrict__ c, _Float16* __restrict__ chs,
                            _Float16* __restrict__ cls, float* __restrict__ c2,
                            int K, int* __restrict__ counter) {
    int t = blockIdx.x * blockDim.x + threadIdx.x;
    if (t == 0) *counter = 0;
    const int nfr = K * 8;
    if (t < nfr) {
        const int k = t >> 3, f = t & 7;
        const int ks = f >> 2, quad = f & 3;
        const int chunk = k >> 6, kc = (k >> 4) & 3, col = k & 15;
        const size_t off = (size_t)chunk * 4096 +
                           (size_t)(((kc * 2 + ks) * 64 + quad * 16 + col) * 8);
        const float* src = c + (size_t)k * D + f * 8;
        f16x8 h, l;
#pragma unroll
        for (int j = 0; j < 8; ++j) {
            float x = src[j];
            _Float16 hs = (_Float16)x;
            h[j] = hs;
            l[j] = (_Float16)((x - (float)hs) * 2048.f);
        }
        *(f16x8*)(chs + off) = h;
        *(f16x8*)(cls + off) = l;
    }
    if (t < K) {
        const float4* cp = (const float4*)(c + (size_t)t * D);
        float s = 0.f;
#pragma unroll
        for (int i = 0; i < D / 4; ++i) {
            float4 v = cp[i];
            s += v.x * v.x; s += v.y * v.y; s += v.z * v.z; s += v.w * v.w;
        }
        c2[t] = s;
    }
}

// Pass 1: fp16-hi/lo MFMA scan over ALL K + top-2 + bin write + near-tie
// flagging + exact fp32 residual for the block's 128 points.
// No LDS staging (r4 lesson: LDS pipe was the bottleneck; the table is
// L1/L2-resident and the swizzled layout makes direct per-lane dwordx4
// loads perfectly coalesced). r5 lesson: chunk-level register double-
// buffering (4 x 32-VGPR sets) blew past the allocator's 128-VGPR grant
// and spilled 345 MB to scratch. THIS REVISION pipelines at 16-centroid
// STEP granularity: two named 16-VGPR B sub-tile sets, depth-1 prefetch,
// ~100 VGPR total demand -> no spill, zero barriers in the main loop.
__global__ __launch_bounds__(256, 2) void pass1_kernel(
    const float* __restrict__ action, const _Float16* __restrict__ chs,
    const _Float16* __restrict__ cls, const float* __restrict__ c2,
    const float* __restrict__ centroids, float* __restrict__ out_bin,
    float* __restrict__ out_res, int* __restrict__ counter,
    int* __restrict__ flags, int N, int K) {
    __shared__ int sbk[128];

    const int tid  = threadIdx.x;
    const int wv   = tid >> 6;
    const int lane = tid & 63;
    const int col  = lane & 15;
    const int quad = lane >> 4;
    const int mb   = blockIdx.x * 128;
    const int m0   = mb + wv * 32;
    const int NT   = K / 16;               // 128 16-centroid steps

    // B-fragment pointers in 16 B units: step t covers centroids
    // [16t, 16t+16); fragment index = t*128 + r*64 + lane.
    const f16x8* gh = (const f16x8*)chs;
    const f16x8* gl = (const f16x8*)cls;

#define LOADP(H0, H1, L0, L1, CC, t_)                                         \
    {                                                                         \
        const int cb = (t_) * 128 + lane;                                     \
        H0 = gh[cb];      H1 = gh[cb + 64];                                   \
        L0 = gl[cb];      L1 = gl[cb + 64];                                   \
        CC = c2[(t_) * 16 + col];                                             \
    }

    f16x8 p0h0, p0h1, p0l0, p0l1, p1h0, p1h1, p1l0, p1l1;
    float cc0, cc1;

    LOADP(p0h0, p0h1, p0l0, p0l1, cc0, 0)   // step 0 in flight under A-conv

    // A fragments: a' = -2a -> fp16 hi + scaled fp16 lo, in registers once.
    f16x8 ah[2][2], al[2][2];
#pragma unroll
    for (int mi = 0; mi < 2; ++mi) {
        const float* arow = action + (size_t)(m0 + mi * 16 + col) * D;
#pragma unroll
        for (int ks = 0; ks < 2; ++ks) {
            const float* src = arow + ks * 32 + quad * 8;
            f16x8 h, l;
#pragma unroll
            for (int j = 0; j < 8; ++j) {
                float x = -2.f * src[j];
                _Float16 hs = (_Float16)x;
                h[j] = hs;
                l[j] = (_Float16)((x - (float)hs) * 2048.f);
            }
            ah[mi][ks] = h;
            al[mi][ks] = l;
        }
    }

    float b1[8], b2[8];
    int   bk[8];
#pragma unroll
    for (int e = 0; e < 8; ++e) {
        b1[e] = __builtin_inff(); b2[e] = __builtin_inff(); bk[e] = 0;
    }

    const f32x4 z4 = {0.f, 0.f, 0.f, 0.f};   // persistent zero C-operand

#define COMPP(H0, H1, L0, L1, CC, t_)                                         \
    {                                                                         \
        const int kk = (t_) * 16 + col;                                       \
        const f32x4 cc4 = {CC, CC, CC, CC};                                   \
        _Pragma("unroll") for (int mi = 0; mi < 2; ++mi) {                    \
            __builtin_amdgcn_s_setprio(1);                                    \
            f32x4 acc2 = __builtin_amdgcn_mfma_f32_16x16x32_f16(al[mi][0], H0, z4, 0, 0, 0);   \
            acc2 = __builtin_amdgcn_mfma_f32_16x16x32_f16(ah[mi][0], L0, acc2, 0, 0, 0);       \
            f32x4 acc1 = __builtin_amdgcn_mfma_f32_16x16x32_f16(ah[mi][0], H0, cc4, 0, 0, 0);  \
            acc2 = __builtin_amdgcn_mfma_f32_16x16x32_f16(al[mi][1], H1, acc2, 0, 0, 0);       \
            acc2 = __builtin_amdgcn_mfma_f32_16x16x32_f16(ah[mi][1], L1, acc2, 0, 0, 0);       \
            acc1 = __builtin_amdgcn_mfma_f32_16x16x32_f16(ah[mi][1], H1, acc1, 0, 0, 0);       \
            __builtin_amdgcn_s_setprio(0);                                    \
            _Pragma("unroll") for (int r = 0; r < 4; ++r) {                   \
                const int e = mi * 4 + r;                                     \
                const float s = fmaf(INVSC, acc2[r], acc1[r]);                \
                b2[e] = __builtin_amdgcn_fmed3f(s, b1[e], b2[e]);             \
                const bool better = s < b1[e];                                \
                b1[e] = fminf(b1[e], s);                                      \
                bk[e] = better ? kk : bk[e];                                  \
            }                                                                 \
        }                                                                     \
    }

    for (int t = 0; t < NT; t += 2) {
        LOADP(p1h0, p1h1, p1l0, p1l1, cc1, t + 1)     // prefetch t+1
        COMPP(p0h0, p0h1, p0l0, p0l1, cc0, t)
        {
            const int nt2 = (t + 2 < NT) ? (t + 2) : (NT - 1);  // tail: dead
            LOADP(p0h0, p0h1, p0l0, p0l1, cc0, nt2)   // prefetch t+2
        }
        COMPP(p1h0, p1h1, p1l0, p1l1, cc1, t + 1)
    }
#undef COMPP
#undef LOADP

    // cross-lane top-2 merge over the 16 centroid columns
#pragma unroll
    for (int off = 1; off < 16; off <<= 1) {
#pragma unroll
        for (int e = 0; e < 8; ++e) {
            float o1 = __shfl_xor(b1[e], off, 64);
            float o2 = __shfl_xor(b2[e], off, 64);
            int   ok = __shfl_xor(bk[e], off, 64);
            bool take = (o1 < b1[e]) || (o1 == b1[e] && ok < bk[e]);
            float nb2 = take ? fminf(b1[e], o2) : fminf(b2[e], o1);
            b1[e] = take ? o1 : b1[e];
            bk[e] = take ? ok : bk[e];
            b2[e] = nb2;
        }
    }

    if (col == 0) {
#pragma unroll
        for (int e = 0; e < 8; ++e) {
            const int mi = e >> 2, r = e & 3;
            const int pl = wv * 32 + mi * 16 + quad * 4 + r;   // 0..127
            sbk[pl] = bk[e];
            out_bin[mb + pl] = (float)bk[e];
            if (b2[e] - b1[e] < EPS) {
                int idx = atomicAdd(counter, 1);
                flags[idx] = mb + pl;
            }
        }
    }
    __syncthreads();

    // exact fp32 residuals for the block's 128 points (2048 float4s).
    // 16 lanes per row -> 256 B contiguous centroid gather, coalesced I/O.
#pragma unroll
    for (int j = 0; j < 8; ++j) {
        const int idx = j * 256 + tid;
        const int row = idx >> 4, c4 = idx & 15;
        const int bki = sbk[row];
        float4 av = ((const float4*)(action + (size_t)(mb + row) * D))[c4];
        float4 cv = ((const float4*)centroids)[bki * 16 + c4];
        ((float4*)(out_res + (size_t)(mb + row) * D))[c4] =
            make_float4(av.x - cv.x, av.y - cv.y, av.z - cv.z, av.w - cv.w);
    }
}

// Exact fp32 rescan for flagged points. Block-per-point grid-stride,
// 4 interleaved dot accumulators for ILP. numpy first-min tie-break.
// (round-0 known-good version; count is ~10 so this is ~3 us)
__global__ __launch_bounds__(256) void exact_kernel(
    const float* __restrict__ action, const float* __restrict__ centroids,
    const float* __restrict__ c2, const int* __restrict__ counter,
    const int* __restrict__ flags, float* __restrict__ out_bin,
    float* __restrict__ out_res, int K) {
    __shared__ float4 sa[D / 4];
    __shared__ float  swv[4];
    __shared__ int    swk[4];
    __shared__ int    s_bk;
    const int count = *counter;
    const int tid = threadIdx.x, lane = tid & 63, wid = tid >> 6;
    for (int i = blockIdx.x; i < count; i += gridDim.x) {
        const int n = flags[i];
        __syncthreads();
        if (tid < D / 4) sa[tid] = ((const float4*)(action + (size_t)n * D))[tid];
        __syncthreads();
        float best = __builtin_inff();
        int bbk = 0x7fffffff;
        for (int k = tid; k < K; k += 256) {
            const float4* cr = (const float4*)(centroids + (size_t)k * D);
            float d0 = 0.f, d1 = 0.f, d2 = 0.f, d3 = 0.f;
#pragma unroll
            for (int q = 0; q < 4; ++q) {
                float4 a0 = sa[q * 4 + 0], c0 = cr[q * 4 + 0];
                float4 a1 = sa[q * 4 + 1], c1 = cr[q * 4 + 1];
                float4 a2 = sa[q * 4 + 2], c2v = cr[q * 4 + 2];
                float4 a3 = sa[q * 4 + 3], c3 = cr[q * 4 + 3];
                d0 = fmaf(a0.x, c0.x, d0); d0 = fmaf(a0.y, c0.y, d0);
                d0 = fmaf(a0.z, c0.z, d0); d0 = fmaf(a0.w, c0.w, d0);
                d1 = fmaf(a1.x, c1.x, d1); d1 = fmaf(a1.y, c1.y, d1);
                d1 = fmaf(a1.z, c1.z, d1); d1 = fmaf(a1.w, c1.w, d1);
                d2 = fmaf(a2.x, c2v.x, d2); d2 = fmaf(a2.y, c2v.y, d2);
                d2 = fmaf(a2.z, c2v.z, d2); d2 = fmaf(a2.w, c2v.w, d2);
                d3 = fmaf(a3.x, c3.x, d3); d3 = fmaf(a3.y, c3.y, d3);
                d3 = fmaf(a3.z, c3.z, d3); d3 = fmaf(a3.w, c3.w, d3);
            }
            float dot = (d0 + d1) + (d2 + d3);
            float s = fmaf(-2.f, dot, c2[k]);
            if (s < best) { best = s; bbk = k; }  // ascending k: first-min
        }
#pragma unroll
        for (int off = 32; off > 0; off >>= 1) {
            float ov = __shfl_down(best, off, 64);
            int   ok = __shfl_down(bbk, off, 64);
            if (ov < best || (ov == best && ok < bbk)) { best = ov; bbk = ok; }
        }
        if (lane == 0) { swv[wid] = best; swk[wid] = bbk; }
        __syncthreads();
        if (tid == 0) {
            float bb = swv[0]; int bki = swk[0];
#pragma unroll
            for (int t = 1; t < 4; ++t)
                if (swv[t] < bb || (swv[t] == bb && swk[t] < bki)) {
                    bb = swv[t]; bki = swk[t];
                }
            out_bin[n] = (float)bki;
            s_bk = bki;
        }
        __syncthreads();
        if (tid < D / 4) {
            float4 a = sa[tid];
            float4 c = ((const float4*)(centroids + (size_t)s_bk * D))[tid];
            ((float4*)(out_res + (size_t)n * D))[tid] =
                make_float4(a.x - c.x, a.y - c.y, a.z - c.z, a.w - c.w);
        }
    }
}

extern "C" void kernel_launch(void* const* d_in, const int* in_sizes, int n_in,
                              void* d_out, int out_size, void* d_ws, size_t ws_size,
                              hipStream_t stream) {
    const float* action    = (const float*)d_in[0];  // [N, 64]
    const float* centroids = (const float*)d_in[1];  // [K, 64]
    const int N = in_sizes[0] / D;  // 65536
    const int K = in_sizes[1] / D;  // 2048

    float* out_bin = (float*)d_out;      // N floats: argmin index
    float* out_res = (float*)d_out + N;  // N*D residuals

    // ws layout (~0.8 MB)
    char* w = (char*)d_ws;
    float*     c2      = (float*)w;                       // 8 KB
    int*       counter = (int*)(w + 8192);                // 4 B (padded to 256)
    int*       flags   = (int*)(w + 8448);                // N*4 = 256 KB
    _Float16*  chs     = (_Float16*)(w + 8448 + 262144);  // K*D*2 = 256 KB (swizzled)
    _Float16*  cls     = chs + (size_t)K * D;             // 256 KB (swizzled)

    prep_kernel<<<(K * 8 + 255) / 256, 256, 0, stream>>>(centroids, chs, cls,
                                                         c2, K, counter);
    pass1_kernel<<<N / 128, 256, 0, stream>>>(action, chs, cls, c2, centroids,
                                              out_bin, out_res, counter, flags,
                                              N, K);
    exact_kernel<<<256, 256, 0, stream>>>(action, centroids, c2, counter, flags,
                                          out_bin, out_res, K);
}